// Round 19
// baseline (122.197 us; speedup 1.0000x reference)
//
#include <hip/hip_runtime.h>

typedef unsigned short u16;
typedef unsigned int u32;
typedef __bf16 bf16x8 __attribute__((ext_vector_type(8)));
typedef float f32x4 __attribute__((ext_vector_type(4)));
typedef float f32x16 __attribute__((ext_vector_type(16)));

#define B_ 16
#define C_ 512
#define N_ 1024
#define NB_ 16384   // B_*N_
#define K_ 512
#define M3_ 1536
#define SCALE_Q 0.18033688011112042f  // 0.125 * log2(e)

// ---- helpers ----
__device__ __forceinline__ u16 f2bf(float f) {
  u32 u = __float_as_uint(f);
  u32 r = (u + 0x7FFFu + ((u >> 16) & 1u)) >> 16;  // RNE
  return (u16)r;
}

__device__ __forceinline__ void gl_lds16(const void* g, void* l) {
  __builtin_amdgcn_global_load_lds(
      (const __attribute__((address_space(1))) u32*)(uintptr_t)g,
      (__attribute__((address_space(3))) u32*)(u32)(uintptr_t)l, 16, 0, 0);
}

__device__ __forceinline__ u32 cvtpk(float lo, float hi) {
  u32 r;
  asm("v_cvt_pk_bf16_f32 %0, %1, %2" : "=v"(r) : "v"(lo), "v"(hi));
  return r;
}

__device__ __forceinline__ float exp2a(float x) {
  float r;
  asm("v_exp_f32 %0, %1" : "=v"(r) : "v"(x));
  return r;
}

// (a,b) -> a' = {a_lo, b_lo}, b' = {a_hi, b_hi}
__device__ __forceinline__ void plswap2(u32& a, u32& b) {
#if __has_builtin(__builtin_amdgcn_permlane32_swap)
  auto r = __builtin_amdgcn_permlane32_swap((int)a, (int)b, false, false);
  a = (u32)r[0];
  b = (u32)r[1];
#else
  asm("v_permlane32_swap_b32 %0, %1" : "+v"(a), "+v"(b));
#endif
}

__device__ __forceinline__ float xhalf_sum(float x) {
  u32 a = __float_as_uint(x), b = a;
  plswap2(a, b);
  return __uint_as_float(a) + __uint_as_float(b);
}

// ---- kernel 1: fused weight-cast (blocks 0..4095) + GroupNorm (4096..4607) ----
__global__ __launch_bounds__(256) void prep_kernel(const float* __restrict__ qkv_w,
                                                   const float* __restrict__ proj_w,
                                                   u16* __restrict__ wq,
                                                   u16* __restrict__ wp,
                                                   const float* __restrict__ x,
                                                   const float* __restrict__ gamma,
                                                   const float* __restrict__ beta,
                                                   u16* __restrict__ ht) {
  int blk0 = blockIdx.x;
  int t = threadIdx.x;
  if (blk0 < 4096) {
    int i = blk0 * 256 + t;
    if (i < M3_ * K_) {
      wq[i] = f2bf(qkv_w[i]);
    } else {
      int j = i - M3_ * K_;
      if (j < C_ * K_) wp[j] = f2bf(proj_w[j]);
    }
    return;
  }
  int blk = blk0 - 4096;
  int b = blk >> 5, g = blk & 31;
  const float* xb = x + ((size_t)(b * C_ + g * 16) << 10);
  float v[16][4];
  float s = 0.f, sq = 0.f;
#pragma unroll
  for (int cc = 0; cc < 16; ++cc) {
#pragma unroll
    for (int r = 0; r < 4; ++r) {
      float f = xb[cc * 1024 + r * 256 + t];
      v[cc][r] = f; s += f; sq += f * f;
    }
  }
#pragma unroll
  for (int m = 32; m >= 1; m >>= 1) { s += __shfl_xor(s, m, 64); sq += __shfl_xor(sq, m, 64); }
  __shared__ float red[8];
  int w = t >> 6;
  if ((t & 63) == 0) { red[w * 2] = s; red[w * 2 + 1] = sq; }
  __syncthreads();
  s = red[0] + red[2] + red[4] + red[6];
  sq = red[1] + red[3] + red[5] + red[7];
  float mean = s * (1.f / 16384.f);
  float var = sq * (1.f / 16384.f) - mean * mean;
  float rstd = rsqrtf(var + 1e-5f);
  float gm[16], bt[16];
#pragma unroll
  for (int cc = 0; cc < 16; ++cc) {
    gm[cc] = gamma[g * 16 + cc] * rstd;
    bt[cc] = beta[g * 16 + cc];
  }
  u16* hb = ht + ((size_t)(b << 10)) * C_ + g * 16;
#pragma unroll
  for (int r = 0; r < 4; ++r) {
    u32 pk[8];
#pragma unroll
    for (int q = 0; q < 8; ++q) {
      float f0 = (v[2 * q][r] - mean) * gm[2 * q] + bt[2 * q];
      float f1 = (v[2 * q + 1][r] - mean) * gm[2 * q + 1] + bt[2 * q + 1];
      pk[q] = (u32)f2bf(f0) | ((u32)f2bf(f1) << 16);
    }
    u16* dp = hb + (size_t)(r * 256 + t) * C_;
    uint4 a = {pk[0], pk[1], pk[2], pk[3]};
    uint4 b4 = {pk[4], pk[5], pk[6], pk[7]};
    *(uint4*)dp = a;
    *(uint4*)(dp + 8) = b4;
  }
}

// ---- GEMM: 16-phase counted-vmcnt pipeline, 128x128 tile ----
// setprio REMOVED (r19 A/B): 4 waves are barrier-lockstep per phase, the
// T5-null/negative regime confirmed by the attn A/B in r18 (m190 mechanism).
// EPI 0: qkv GEMM. q,k bands (rows<1024) stored TRANSPOSED per-(b,h) as (n,d)
//        bf16 into qTo/kTo (q pre-scaled); v band stored (o, bn) in Co.
// EPI 1: out = x + val + bias -> fp32 (b,c,n)
template <int EPI>
__global__ __launch_bounds__(256) void gemm_kernel(const u16* __restrict__ A,
                                                   const u16* __restrict__ BT,
                                                   const float* __restrict__ bias,
                                                   u16* __restrict__ Co,
                                                   u16* __restrict__ qTo,
                                                   u16* __restrict__ kTo,
                                                   const float* __restrict__ xres,
                                                   float* __restrict__ Fo) {
  __shared__ __attribute__((aligned(16))) u16 lds[4][8192];  // [half-buf][A:0..4095 | B:4096..8191]
  int t = threadIdx.x;
  int l = t & 63, w = t >> 6;
  int wr = w >> 1, wc = w & 1;
  int lid = blockIdx.y * 128 + blockIdx.x;
  int xcd = lid & 7, j2 = lid >> 3;
  int bx = xcd * 16 + (j2 & 15);
  int by = j2 >> 4;
  int ro0 = by * 128, co0 = bx * 128;
  f32x4 acc[4][4];
#pragma unroll
  for (int m = 0; m < 4; ++m)
#pragma unroll
    for (int n = 0; n < 4; ++n) acc[m][n] = {0.f, 0.f, 0.f, 0.f};

  int gsrc = ((l & 3) ^ ((l >> 3) & 3)) * 8;
  const u16* sA0 = A + (size_t)(ro0 + 2 * w * 16 + (l >> 2)) * K_ + gsrc;
  const u16* sA1 = sA0 + (size_t)16 * K_;
  const u16* sB0 = BT + (size_t)(co0 + 2 * w * 16 + (l >> 2)) * K_ + gsrc;
  const u16* sB1 = sB0 + (size_t)16 * K_;
  u32 dA0 = (2 * w) * 512, dA1 = (2 * w + 1) * 512;
  u32 dB0 = 4096 + (2 * w) * 512, dB1 = 4096 + (2 * w + 1) * 512;

  auto stage = [&](int hb) {
    u16* base = &lds[hb][0];
    gl_lds16(sA0, base + dA0);
    gl_lds16(sA1, base + dA1);
    gl_lds16(sB0, base + dB0);
    gl_lds16(sB1, base + dB1);
    sA0 += 32; sA1 += 32; sB0 += 32; sB1 += 32;
  };

  u32 slot = (((l >> 4) ^ (l >> 1)) & 3) * 8;
  u32 aro = (wr * 64 + (l & 15)) * 32 + slot;
  u32 bro = 4096 + (wc * 64 + (l & 15)) * 32 + slot;

  auto compute = [&](int hb) {
    const u16* base = &lds[hb][0];
    bf16x8 af[4], bfr[4];
#pragma unroll
    for (int m = 0; m < 4; ++m) af[m] = *(const bf16x8*)(base + aro + m * 512);
#pragma unroll
    for (int n = 0; n < 4; ++n) bfr[n] = *(const bf16x8*)(base + bro + n * 512);
#pragma unroll
    for (int m = 0; m < 4; ++m)
#pragma unroll
      for (int n = 0; n < 4; ++n)
        acc[m][n] = __builtin_amdgcn_mfma_f32_16x16x32_bf16(af[m], bfr[n], acc[m][n], 0, 0, 0);
  };

#define PHASE_SYNC(N)                                    \
  asm volatile("s_waitcnt vmcnt(" #N ")" ::: "memory"); \
  __builtin_amdgcn_sched_barrier(0);                     \
  __builtin_amdgcn_s_barrier();                          \
  __builtin_amdgcn_sched_barrier(0);

  stage(0);
  stage(1);
  stage(2);
#pragma unroll 1
  for (int h = 0; h < 13; ++h) {
    PHASE_SYNC(8)
    stage((h + 3) & 3);
    compute(h & 3);
  }
  PHASE_SYNC(8)
  compute(1);  // h=13
  PHASE_SYNC(4)
  compute(2);  // h=14
  PHASE_SYNC(0)
  compute(3);  // h=15
#undef PHASE_SYNC

  if (EPI == 0 && ro0 < 1024) {
    int sel = ro0 >> 9;
    u16* dstb = sel ? kTo : qTo;
    float scl = sel ? 1.f : SCALE_Q;
#pragma unroll
    for (int m = 0; m < 4; ++m) {
      int row0 = ro0 + wr * 64 + m * 16 + (l >> 4) * 4;
      int o = row0 & 511;
      int h2 = o >> 6, d0 = o & 63;
      float bv0 = bias[row0], bv1 = bias[row0 + 1];
      float bv2 = bias[row0 + 2], bv3 = bias[row0 + 3];
#pragma unroll
      for (int n = 0; n < 4; ++n) {
        int col = co0 + wc * 64 + n * 16 + (l & 15);
        int bb = col >> 10, nn = col & 1023;
        float v0 = (acc[m][n][0] + bv0) * scl;
        float v1 = (acc[m][n][1] + bv1) * scl;
        float v2 = (acc[m][n][2] + bv2) * scl;
        float v3 = (acc[m][n][3] + bv3) * scl;
        uint2 ov = {cvtpk(v0, v1), cvtpk(v2, v3)};
        *(uint2*)(dstb + ((size_t)((bb * 8 + h2) << 10) + nn) * 64 + d0) = ov;
      }
    }
  } else {
#pragma unroll
    for (int m = 0; m < 4; ++m) {
#pragma unroll
      for (int j = 0; j < 4; ++j) {
        int row = ro0 + wr * 64 + m * 16 + (l >> 4) * 4 + j;
        float bv = bias[row];
#pragma unroll
        for (int n = 0; n < 4; ++n) {
          int col = co0 + wc * 64 + n * 16 + (l & 15);
          float val = acc[m][n][j] + bv;
          if (EPI == 0) {
            Co[(size_t)row * NB_ + col] = f2bf(val);
          } else {
            int bb = col >> 10, nn = col & 1023;
            size_t oi = (((size_t)(bb * C_ + row)) << 10) + nn;
            Fo[oi] = xres[oi] + val;
          }
        }
      }
    }
  }
}

// ---- kernel 4: flash attention, 4 waves x 32 q-rows, KVBLK=32, T15 pipeline ----
// (r18-exact: best measured attn, ~50.9us, no setprio)
__global__ __launch_bounds__(256) void attn_kernel(const u16* __restrict__ qT,
                                                   const u16* __restrict__ kT,
                                                   const u16* __restrict__ qkv,
                                                   u16* __restrict__ aoT) {
  __shared__ u16 KV[3][4096];  // [buf][0..2047 = K(32kv x 64d) | 2048..4095 = V(64d x 32kv)]
  int bid = blockIdx.x;
  int wid = (bid & 7) * 128 + (bid >> 3);  // XCD swizzle: 8 blocks of a head on one XCD
  int qt2 = wid & 7, h = (wid >> 3) & 7, b = wid >> 6;
  int bh = b * 8 + h;
  int t = threadIdx.x, l = t & 63, w = t >> 6;
  int lq = l & 31, hi = l >> 5;
  int q0 = qt2 * 128 + w * 32;

  const u16* qbase = qT + ((size_t)(bh << 10) + q0 + lq) * 64 + hi * 8;
  bf16x8 qf[4];
#pragma unroll
  for (int kc = 0; kc < 4; ++kc) qf[kc] = *(const bf16x8*)(qbase + kc * 16);

  f32x16 accO[2];
#pragma unroll
  for (int dt = 0; dt < 2; ++dt)
#pragma unroll
    for (int r = 0; r < 16; ++r) accO[dt][r] = 0.f;
  float lsum = 0.f;

  const u16 *src0, *src1;
  u32 ldso0, ldso1;
  int adv;
  if (w < 2) {
    int i0 = 2 * w, i1 = 2 * w + 1;
    src0 = kT + ((size_t)(bh << 10) + i0 * 8 + (l >> 3)) * 64 + (((l & 7) ^ ((l >> 3) & 7)) * 8);
    src1 = kT + ((size_t)(bh << 10) + i1 * 8 + (l >> 3)) * 64 + (((l & 7) ^ ((l >> 3) & 7)) * 8);
    ldso0 = i0 * 512; ldso1 = i1 * 512;
    adv = 2048;  // 32 kv-rows * 64
  } else {
    int j0 = 2 * (w - 2), j1 = 2 * (w - 2) + 1;
    src0 = qkv + (size_t)(2 * C_ + h * 64 + j0 * 16 + (l >> 2)) * NB_ + (b << 10) +
           (((l & 3) ^ ((l >> 3) & 3)) * 8);
    src1 = qkv + (size_t)(2 * C_ + h * 64 + j1 * 16 + (l >> 2)) * NB_ + (b << 10) +
           (((l & 3) ^ ((l >> 3) & 3)) * 8);
    ldso0 = 2048 + j0 * 512; ldso1 = 2048 + j1 * 512;
    adv = 32;    // 32 kv-cols
  }

  u32 kfo[4], vfo[4];
#pragma unroll
  for (int kc = 0; kc < 4; ++kc)
    kfo[kc] = lq * 64 + (((2 * kc + hi) ^ (lq & 7)) * 8);
#pragma unroll
  for (int dt = 0; dt < 2; ++dt)
#pragma unroll
    for (int kcc = 0; kcc < 2; ++kcc)
      vfo[dt * 2 + kcc] = 2048 + (dt * 32 + lq) * 32 + (((kcc * 2 + hi) ^ ((lq >> 1) & 3)) * 8);

  auto stageTo = [&](u16* buf) {
    gl_lds16(src0, buf + ldso0);
    gl_lds16(src1, buf + ldso1);
    src0 += adv;
    src1 += adv;
  };

  auto qk = [&](const u16* buf, f32x16& sc) {
    bf16x8 kf[4];
#pragma unroll
    for (int kc = 0; kc < 4; ++kc) kf[kc] = *(const bf16x8*)(buf + kfo[kc]);
#pragma unroll
    for (int r = 0; r < 16; ++r) sc[r] = 0.f;
#pragma unroll
    for (int kc = 0; kc < 4; ++kc)
      sc = __builtin_amdgcn_mfma_f32_32x32x16_bf16(kf[kc], qf[kc], sc, 0, 0, 0);
  };

  auto finish = [&](const u16* buf, f32x16& sc) {
    bf16x8 vf[4];
#pragma unroll
    for (int j = 0; j < 4; ++j) vf[j] = *(const bf16x8*)(buf + vfo[j]);
    float p0 = 0.f, p1 = 0.f, p2 = 0.f, p3 = 0.f;
#pragma unroll
    for (int r = 0; r < 4; ++r) {
      float e0 = exp2a(sc[4 * r + 0]);
      float e1 = exp2a(sc[4 * r + 1]);
      float e2 = exp2a(sc[4 * r + 2]);
      float e3 = exp2a(sc[4 * r + 3]);
      sc[4 * r + 0] = e0; sc[4 * r + 1] = e1;
      sc[4 * r + 2] = e2; sc[4 * r + 3] = e3;
      p0 += e0; p1 += e1; p2 += e2; p3 += e3;
    }
    lsum += (p0 + p1) + (p2 + p3);
    u32 pk[8];
#pragma unroll
    for (int p = 0; p < 8; ++p) pk[p] = cvtpk(sc[2 * p], sc[2 * p + 1]);
    u32 pfu[2][4];
#pragma unroll
    for (int cc = 0; cc < 2; ++cc) {
      u32 w0 = pk[cc * 4 + 0], w2 = pk[cc * 4 + 2];
      u32 w1 = pk[cc * 4 + 1], w3 = pk[cc * 4 + 3];
      plswap2(w0, w2);
      plswap2(w1, w3);
      pfu[cc][0] = w0; pfu[cc][1] = w1; pfu[cc][2] = w2; pfu[cc][3] = w3;
    }
#pragma unroll
    for (int kcc = 0; kcc < 2; ++kcc)
#pragma unroll
      for (int dt = 0; dt < 2; ++dt) {
        union { u32 u[4]; bf16x8 v; } pf;
        pf.u[0] = pfu[kcc][0]; pf.u[1] = pfu[kcc][1];
        pf.u[2] = pfu[kcc][2]; pf.u[3] = pfu[kcc][3];
        accO[dt] = __builtin_amdgcn_mfma_f32_32x32x16_bf16(vf[dt * 2 + kcc], pf.v, accO[dt], 0, 0, 0);
      }
  };

#define WAITBAR(N)                                       \
  asm volatile("s_waitcnt vmcnt(" #N ")" ::: "memory"); \
  __builtin_amdgcn_sched_barrier(0);                     \
  __builtin_amdgcn_s_barrier();                          \
  __builtin_amdgcn_sched_barrier(0);

  u16* pa = &KV[0][0];
  u16* pb = &KV[1][0];
  u16* pc = &KV[2][0];
  f32x16 scA, scB;

  stageTo(pa);  // tile 0
  stageTo(pb);  // tile 1
  WAITBAR(0)
  qk(pa, scA);  // QK(0)

#pragma unroll 1
  for (int s = 0; s < 15; ++s) {
    WAITBAR(0)
    stageTo(pc);
    qk(pb, scB);
    finish(pa, scA);
    u16* tp = pa; pa = pb; pb = pc; pc = tp;
    WAITBAR(0)
    stageTo(pc);
    qk(pb, scA);
    finish(pa, scB);
    tp = pa; pa = pb; pb = pc; pc = tp;
  }
  WAITBAR(0)
  qk(pb, scB);
  finish(pa, scA);
  pa = pb;
  finish(pa, scB);
#undef WAITBAR

  float inv = 1.0f / xhalf_sum(lsum);
  u16* ob = aoT + ((size_t)((b << 10) + q0 + lq)) * C_ + h * 64;
#pragma unroll
  for (int dt = 0; dt < 2; ++dt)
#pragma unroll
    for (int rg = 0; rg < 4; ++rg) {
      int d0 = dt * 32 + rg * 8 + hi * 4;
      u32 w0 = cvtpk(accO[dt][rg * 4 + 0] * inv, accO[dt][rg * 4 + 1] * inv);
      u32 w1 = cvtpk(accO[dt][rg * 4 + 2] * inv, accO[dt][rg * 4 + 3] * inv);
      uint2 o = {w0, w1};
      *(uint2*)(ob + d0) = o;
    }
}

// ---- launcher ----
extern "C" void kernel_launch(void* const* d_in, const int* in_sizes, int n_in,
                              void* d_out, int out_size, void* d_ws, size_t ws_size,
                              hipStream_t stream) {
  const float* x = (const float*)d_in[0];
  const float* gamma = (const float*)d_in[1];
  const float* beta = (const float*)d_in[2];
  const float* qkv_w = (const float*)d_in[3];
  const float* qkv_b = (const float*)d_in[4];
  const float* proj_w = (const float*)d_in[5];
  const float* proj_b = (const float*)d_in[6];
  float* out = (float*)d_out;
  char* ws = (char*)d_ws;
  u16* wq = (u16*)(ws);                      // 1,572,864
  u16* wp = (u16*)(ws + 1572864);            //   524,288
  u16* ht = (u16*)(ws + 2097152);            // 16,777,216 (reused as aoT)
  u16* qkvo = (u16*)(ws + 18874368);         // 50,331,648 (only v band used)
  u16* qT = (u16*)(ws + 69206016);           // 16,777,216
  u16* kT = (u16*)(ws + 85983232);           // 16,777,216
  u16* aoT = ht;

  prep_kernel<<<4608, 256, 0, stream>>>(qkv_w, proj_w, wq, wp, x, gamma, beta, ht);
  gemm_kernel<0><<<dim3(128, 12), 256, 0, stream>>>(wq, ht, qkv_b, qkvo, qT, kT, nullptr, nullptr);
  attn_kernel<<<1024, 256, 0, stream>>>(qT, kT, qkvo, aoT);
  gemm_kernel<1><<<dim3(128, 4), 256, 0, stream>>>(wp, aoT, proj_b, nullptr, nullptr, nullptr, x, out);
}

// Round 20
// 119.483 us; speedup vs baseline: 1.0227x; 1.0227x over previous
//
#include <hip/hip_runtime.h>

typedef unsigned short u16;
typedef unsigned int u32;
typedef __bf16 bf16x8 __attribute__((ext_vector_type(8)));
typedef float f32x4 __attribute__((ext_vector_type(4)));
typedef float f32x16 __attribute__((ext_vector_type(16)));

#define B_ 16
#define C_ 512
#define N_ 1024
#define NB_ 16384   // B_*N_
#define K_ 512
#define M3_ 1536
#define SCALE_Q 0.18033688011112042f  // 0.125 * log2(e)

// ---- helpers ----
__device__ __forceinline__ u16 f2bf(float f) {
  u32 u = __float_as_uint(f);
  u32 r = (u + 0x7FFFu + ((u >> 16) & 1u)) >> 16;  // RNE
  return (u16)r;
}

__device__ __forceinline__ void gl_lds16(const void* g, void* l) {
  __builtin_amdgcn_global_load_lds(
      (const __attribute__((address_space(1))) u32*)(uintptr_t)g,
      (__attribute__((address_space(3))) u32*)(u32)(uintptr_t)l, 16, 0, 0);
}

__device__ __forceinline__ u32 cvtpk(float lo, float hi) {
  u32 r;
  asm("v_cvt_pk_bf16_f32 %0, %1, %2" : "=v"(r) : "v"(lo), "v"(hi));
  return r;
}

__device__ __forceinline__ float exp2a(float x) {
  float r;
  asm("v_exp_f32 %0, %1" : "=v"(r) : "v"(x));
  return r;
}

// (a,b) -> a' = {a_lo, b_lo}, b' = {a_hi, b_hi}
__device__ __forceinline__ void plswap2(u32& a, u32& b) {
#if __has_builtin(__builtin_amdgcn_permlane32_swap)
  auto r = __builtin_amdgcn_permlane32_swap((int)a, (int)b, false, false);
  a = (u32)r[0];
  b = (u32)r[1];
#else
  asm("v_permlane32_swap_b32 %0, %1" : "+v"(a), "+v"(b));
#endif
}

__device__ __forceinline__ float xhalf_sum(float x) {
  u32 a = __float_as_uint(x), b = a;
  plswap2(a, b);
  return __uint_as_float(a) + __uint_as_float(b);
}

// ---- kernel 1: fused weight-cast (blocks 0..4095) + GroupNorm (4096..4607) ----
__global__ __launch_bounds__(256) void prep_kernel(const float* __restrict__ qkv_w,
                                                   const float* __restrict__ proj_w,
                                                   u16* __restrict__ wq,
                                                   u16* __restrict__ wp,
                                                   const float* __restrict__ x,
                                                   const float* __restrict__ gamma,
                                                   const float* __restrict__ beta,
                                                   u16* __restrict__ ht) {
  int blk0 = blockIdx.x;
  int t = threadIdx.x;
  if (blk0 < 4096) {
    int i = blk0 * 256 + t;
    if (i < M3_ * K_) {
      wq[i] = f2bf(qkv_w[i]);
    } else {
      int j = i - M3_ * K_;
      if (j < C_ * K_) wp[j] = f2bf(proj_w[j]);
    }
    return;
  }
  int blk = blk0 - 4096;
  int b = blk >> 5, g = blk & 31;
  const float* xb = x + ((size_t)(b * C_ + g * 16) << 10);
  float v[16][4];
  float s = 0.f, sq = 0.f;
#pragma unroll
  for (int cc = 0; cc < 16; ++cc) {
#pragma unroll
    for (int r = 0; r < 4; ++r) {
      float f = xb[cc * 1024 + r * 256 + t];
      v[cc][r] = f; s += f; sq += f * f;
    }
  }
#pragma unroll
  for (int m = 32; m >= 1; m >>= 1) { s += __shfl_xor(s, m, 64); sq += __shfl_xor(sq, m, 64); }
  __shared__ float red[8];
  int w = t >> 6;
  if ((t & 63) == 0) { red[w * 2] = s; red[w * 2 + 1] = sq; }
  __syncthreads();
  s = red[0] + red[2] + red[4] + red[6];
  sq = red[1] + red[3] + red[5] + red[7];
  float mean = s * (1.f / 16384.f);
  float var = sq * (1.f / 16384.f) - mean * mean;
  float rstd = rsqrtf(var + 1e-5f);
  float gm[16], bt[16];
#pragma unroll
  for (int cc = 0; cc < 16; ++cc) {
    gm[cc] = gamma[g * 16 + cc] * rstd;
    bt[cc] = beta[g * 16 + cc];
  }
  u16* hb = ht + ((size_t)(b << 10)) * C_ + g * 16;
#pragma unroll
  for (int r = 0; r < 4; ++r) {
    u32 pk[8];
#pragma unroll
    for (int q = 0; q < 8; ++q) {
      float f0 = (v[2 * q][r] - mean) * gm[2 * q] + bt[2 * q];
      float f1 = (v[2 * q + 1][r] - mean) * gm[2 * q + 1] + bt[2 * q + 1];
      pk[q] = (u32)f2bf(f0) | ((u32)f2bf(f1) << 16);
    }
    u16* dp = hb + (size_t)(r * 256 + t) * C_;
    uint4 a = {pk[0], pk[1], pk[2], pk[3]};
    uint4 b4 = {pk[4], pk[5], pk[6], pk[7]};
    *(uint4*)dp = a;
    *(uint4*)(dp + 8) = b4;
  }
}

// ---- GEMM (r18-exact): 16-phase counted-vmcnt pipeline, 128x128 tile ----
// EPI 0: qkv GEMM. q,k bands (rows<1024) stored TRANSPOSED per-(b,h) as (n,d)
//        bf16 into qTo/kTo (q pre-scaled); v band stored (o, bn) in Co.
// EPI 1: out = x + val + bias -> fp32 (b,c,n)
template <int EPI>
__global__ __launch_bounds__(256) void gemm_kernel(const u16* __restrict__ A,
                                                   const u16* __restrict__ BT,
                                                   const float* __restrict__ bias,
                                                   u16* __restrict__ Co,
                                                   u16* __restrict__ qTo,
                                                   u16* __restrict__ kTo,
                                                   const float* __restrict__ xres,
                                                   float* __restrict__ Fo) {
  __shared__ __attribute__((aligned(16))) u16 lds[4][8192];  // [half-buf][A:0..4095 | B:4096..8191]
  int t = threadIdx.x;
  int l = t & 63, w = t >> 6;
  int wr = w >> 1, wc = w & 1;
  int lid = blockIdx.y * 128 + blockIdx.x;
  int xcd = lid & 7, j2 = lid >> 3;
  int bx = xcd * 16 + (j2 & 15);
  int by = j2 >> 4;
  int ro0 = by * 128, co0 = bx * 128;
  f32x4 acc[4][4];
#pragma unroll
  for (int m = 0; m < 4; ++m)
#pragma unroll
    for (int n = 0; n < 4; ++n) acc[m][n] = {0.f, 0.f, 0.f, 0.f};

  int gsrc = ((l & 3) ^ ((l >> 3) & 3)) * 8;
  const u16* sA0 = A + (size_t)(ro0 + 2 * w * 16 + (l >> 2)) * K_ + gsrc;
  const u16* sA1 = sA0 + (size_t)16 * K_;
  const u16* sB0 = BT + (size_t)(co0 + 2 * w * 16 + (l >> 2)) * K_ + gsrc;
  const u16* sB1 = sB0 + (size_t)16 * K_;
  u32 dA0 = (2 * w) * 512, dA1 = (2 * w + 1) * 512;
  u32 dB0 = 4096 + (2 * w) * 512, dB1 = 4096 + (2 * w + 1) * 512;

  auto stage = [&](int hb) {
    u16* base = &lds[hb][0];
    gl_lds16(sA0, base + dA0);
    gl_lds16(sA1, base + dA1);
    gl_lds16(sB0, base + dB0);
    gl_lds16(sB1, base + dB1);
    sA0 += 32; sA1 += 32; sB0 += 32; sB1 += 32;
  };

  u32 slot = (((l >> 4) ^ (l >> 1)) & 3) * 8;
  u32 aro = (wr * 64 + (l & 15)) * 32 + slot;
  u32 bro = 4096 + (wc * 64 + (l & 15)) * 32 + slot;

  auto compute = [&](int hb) {
    const u16* base = &lds[hb][0];
    bf16x8 af[4], bfr[4];
#pragma unroll
    for (int m = 0; m < 4; ++m) af[m] = *(const bf16x8*)(base + aro + m * 512);
#pragma unroll
    for (int n = 0; n < 4; ++n) bfr[n] = *(const bf16x8*)(base + bro + n * 512);
    __builtin_amdgcn_s_setprio(1);
#pragma unroll
    for (int m = 0; m < 4; ++m)
#pragma unroll
      for (int n = 0; n < 4; ++n)
        acc[m][n] = __builtin_amdgcn_mfma_f32_16x16x32_bf16(af[m], bfr[n], acc[m][n], 0, 0, 0);
    __builtin_amdgcn_s_setprio(0);
  };

#define PHASE_SYNC(N)                                    \
  asm volatile("s_waitcnt vmcnt(" #N ")" ::: "memory"); \
  __builtin_amdgcn_sched_barrier(0);                     \
  __builtin_amdgcn_s_barrier();                          \
  __builtin_amdgcn_sched_barrier(0);

  stage(0);
  stage(1);
  stage(2);
#pragma unroll 1
  for (int h = 0; h < 13; ++h) {
    PHASE_SYNC(8)
    stage((h + 3) & 3);
    compute(h & 3);
  }
  PHASE_SYNC(8)
  compute(1);  // h=13
  PHASE_SYNC(4)
  compute(2);  // h=14
  PHASE_SYNC(0)
  compute(3);  // h=15
#undef PHASE_SYNC

  if (EPI == 0 && ro0 < 1024) {
    int sel = ro0 >> 9;
    u16* dstb = sel ? kTo : qTo;
    float scl = sel ? 1.f : SCALE_Q;
#pragma unroll
    for (int m = 0; m < 4; ++m) {
      int row0 = ro0 + wr * 64 + m * 16 + (l >> 4) * 4;
      int o = row0 & 511;
      int h2 = o >> 6, d0 = o & 63;
      float bv0 = bias[row0], bv1 = bias[row0 + 1];
      float bv2 = bias[row0 + 2], bv3 = bias[row0 + 3];
#pragma unroll
      for (int n = 0; n < 4; ++n) {
        int col = co0 + wc * 64 + n * 16 + (l & 15);
        int bb = col >> 10, nn = col & 1023;
        float v0 = (acc[m][n][0] + bv0) * scl;
        float v1 = (acc[m][n][1] + bv1) * scl;
        float v2 = (acc[m][n][2] + bv2) * scl;
        float v3 = (acc[m][n][3] + bv3) * scl;
        uint2 ov = {cvtpk(v0, v1), cvtpk(v2, v3)};
        *(uint2*)(dstb + ((size_t)((bb * 8 + h2) << 10) + nn) * 64 + d0) = ov;
      }
    }
  } else {
#pragma unroll
    for (int m = 0; m < 4; ++m) {
#pragma unroll
      for (int j = 0; j < 4; ++j) {
        int row = ro0 + wr * 64 + m * 16 + (l >> 4) * 4 + j;
        float bv = bias[row];
#pragma unroll
        for (int n = 0; n < 4; ++n) {
          int col = co0 + wc * 64 + n * 16 + (l & 15);
          float val = acc[m][n][j] + bv;
          if (EPI == 0) {
            Co[(size_t)row * NB_ + col] = f2bf(val);
          } else {
            int bb = col >> 10, nn = col & 1023;
            size_t oi = (((size_t)(bb * C_ + row)) << 10) + nn;
            Fo[oi] = xres[oi] + val;
          }
        }
      }
    }
  }
}

// ---- kernel 4: flash attention, 8 waves x 32 q-rows (256 q/block), KVBLK=32 ----
// T15 pipeline, no setprio (r18). One shared KV stream per block now feeds 8
// waves: K/V re-read from L2 only 4x per head (was 8x), and staging is 1
// global_load_lds per wave per step (was 2). Per-wave math, fragment offsets,
// and WAITBAR discipline byte-identical to r18.
__global__ __launch_bounds__(512) void attn_kernel(const u16* __restrict__ qT,
                                                   const u16* __restrict__ kT,
                                                   const u16* __restrict__ qkv,
                                                   u16* __restrict__ aoT) {
  __shared__ u16 KV[3][4096];  // [buf][0..2047 = K(32kv x 64d) | 2048..4095 = V(64d x 32kv)]
  int bid = blockIdx.x;
  int wid = (bid & 7) * 64 + (bid >> 3);  // XCD swizzle (512 blocks, 8 XCDs)
  int qt2 = wid & 3, h = (wid >> 2) & 7, b = wid >> 5;
  int bh = b * 8 + h;
  int t = threadIdx.x, l = t & 63, w = t >> 6;  // w in 0..7
  int lq = l & 31, hi = l >> 5;
  int q0 = qt2 * 256 + w * 32;

  const u16* qbase = qT + ((size_t)(bh << 10) + q0 + lq) * 64 + hi * 8;
  bf16x8 qf[4];
#pragma unroll
  for (int kc = 0; kc < 4; ++kc) qf[kc] = *(const bf16x8*)(qbase + kc * 16);

  f32x16 accO[2];
#pragma unroll
  for (int dt = 0; dt < 2; ++dt)
#pragma unroll
    for (int r = 0; r < 16; ++r) accO[dt][r] = 0.f;
  float lsum = 0.f;

  // staging: 8 gl_lds16 per tile, wave w issues exactly 1.
  // waves 0-3: K instr i0=w (rows i0*8 + (l>>3)); waves 4-7: V instr j0=w-4
  // (d-rows j0*16 + (l>>2)). Same address/swizzle math as r18.
  const u16* src0;
  u32 ldso0;
  int adv;
  if (w < 4) {
    int i0 = w;
    src0 = kT + ((size_t)(bh << 10) + i0 * 8 + (l >> 3)) * 64 + (((l & 7) ^ ((l >> 3) & 7)) * 8);
    ldso0 = i0 * 512;
    adv = 2048;  // 32 kv-rows * 64
  } else {
    int j0 = w - 4;
    src0 = qkv + (size_t)(2 * C_ + h * 64 + j0 * 16 + (l >> 2)) * NB_ + (b << 10) +
           (((l & 3) ^ ((l >> 3) & 3)) * 8);
    ldso0 = 2048 + j0 * 512;
    adv = 32;    // 32 kv-cols
  }

  u32 kfo[4], vfo[4];
#pragma unroll
  for (int kc = 0; kc < 4; ++kc)
    kfo[kc] = lq * 64 + (((2 * kc + hi) ^ (lq & 7)) * 8);
#pragma unroll
  for (int dt = 0; dt < 2; ++dt)
#pragma unroll
    for (int kcc = 0; kcc < 2; ++kcc)
      vfo[dt * 2 + kcc] = 2048 + (dt * 32 + lq) * 32 + (((kcc * 2 + hi) ^ ((lq >> 1) & 3)) * 8);

  auto stageTo = [&](u16* buf) {
    gl_lds16(src0, buf + ldso0);
    src0 += adv;
  };

  auto qk = [&](const u16* buf, f32x16& sc) {
    bf16x8 kf[4];
#pragma unroll
    for (int kc = 0; kc < 4; ++kc) kf[kc] = *(const bf16x8*)(buf + kfo[kc]);
#pragma unroll
    for (int r = 0; r < 16; ++r) sc[r] = 0.f;
#pragma unroll
    for (int kc = 0; kc < 4; ++kc)
      sc = __builtin_amdgcn_mfma_f32_32x32x16_bf16(kf[kc], qf[kc], sc, 0, 0, 0);
  };

  auto finish = [&](const u16* buf, f32x16& sc) {
    bf16x8 vf[4];
#pragma unroll
    for (int j = 0; j < 4; ++j) vf[j] = *(const bf16x8*)(buf + vfo[j]);
    float p0 = 0.f, p1 = 0.f, p2 = 0.f, p3 = 0.f;
#pragma unroll
    for (int r = 0; r < 4; ++r) {
      float e0 = exp2a(sc[4 * r + 0]);
      float e1 = exp2a(sc[4 * r + 1]);
      float e2 = exp2a(sc[4 * r + 2]);
      float e3 = exp2a(sc[4 * r + 3]);
      sc[4 * r + 0] = e0; sc[4 * r + 1] = e1;
      sc[4 * r + 2] = e2; sc[4 * r + 3] = e3;
      p0 += e0; p1 += e1; p2 += e2; p3 += e3;
    }
    lsum += (p0 + p1) + (p2 + p3);
    u32 pk[8];
#pragma unroll
    for (int p = 0; p < 8; ++p) pk[p] = cvtpk(sc[2 * p], sc[2 * p + 1]);
    u32 pfu[2][4];
#pragma unroll
    for (int cc = 0; cc < 2; ++cc) {
      u32 w0 = pk[cc * 4 + 0], w2 = pk[cc * 4 + 2];
      u32 w1 = pk[cc * 4 + 1], w3 = pk[cc * 4 + 3];
      plswap2(w0, w2);
      plswap2(w1, w3);
      pfu[cc][0] = w0; pfu[cc][1] = w1; pfu[cc][2] = w2; pfu[cc][3] = w3;
    }
#pragma unroll
    for (int kcc = 0; kcc < 2; ++kcc)
#pragma unroll
      for (int dt = 0; dt < 2; ++dt) {
        union { u32 u[4]; bf16x8 v; } pf;
        pf.u[0] = pfu[kcc][0]; pf.u[1] = pfu[kcc][1];
        pf.u[2] = pfu[kcc][2]; pf.u[3] = pfu[kcc][3];
        accO[dt] = __builtin_amdgcn_mfma_f32_32x32x16_bf16(vf[dt * 2 + kcc], pf.v, accO[dt], 0, 0, 0);
      }
  };

#define WAITBAR(N)                                       \
  asm volatile("s_waitcnt vmcnt(" #N ")" ::: "memory"); \
  __builtin_amdgcn_sched_barrier(0);                     \
  __builtin_amdgcn_s_barrier();                          \
  __builtin_amdgcn_sched_barrier(0);

  u16* pa = &KV[0][0];
  u16* pb = &KV[1][0];
  u16* pc = &KV[2][0];
  f32x16 scA, scB;

  stageTo(pa);  // tile 0
  stageTo(pb);  // tile 1
  WAITBAR(0)
  qk(pa, scA);  // QK(0)

#pragma unroll 1
  for (int s = 0; s < 15; ++s) {
    WAITBAR(0)
    stageTo(pc);
    qk(pb, scB);
    finish(pa, scA);
    u16* tp = pa; pa = pb; pb = pc; pc = tp;
    WAITBAR(0)
    stageTo(pc);
    qk(pb, scA);
    finish(pa, scB);
    tp = pa; pa = pb; pb = pc; pc = tp;
  }
  WAITBAR(0)
  qk(pb, scB);
  finish(pa, scA);
  pa = pb;
  finish(pa, scB);
#undef WAITBAR

  float inv = 1.0f / xhalf_sum(lsum);
  u16* ob = aoT + ((size_t)((b << 10) + q0 + lq)) * C_ + h * 64;
#pragma unroll
  for (int dt = 0; dt < 2; ++dt)
#pragma unroll
    for (int rg = 0; rg < 4; ++rg) {
      int d0 = dt * 32 + rg * 8 + hi * 4;
      u32 w0 = cvtpk(accO[dt][rg * 4 + 0] * inv, accO[dt][rg * 4 + 1] * inv);
      u32 w1 = cvtpk(accO[dt][rg * 4 + 2] * inv, accO[dt][rg * 4 + 3] * inv);
      uint2 o = {w0, w1};
      *(uint2*)(ob + d0) = o;
    }
}

// ---- launcher ----
extern "C" void kernel_launch(void* const* d_in, const int* in_sizes, int n_in,
                              void* d_out, int out_size, void* d_ws, size_t ws_size,
                              hipStream_t stream) {
  const float* x = (const float*)d_in[0];
  const float* gamma = (const float*)d_in[1];
  const float* beta = (const float*)d_in[2];
  const float* qkv_w = (const float*)d_in[3];
  const float* qkv_b = (const float*)d_in[4];
  const float* proj_w = (const float*)d_in[5];
  const float* proj_b = (const float*)d_in[6];
  float* out = (float*)d_out;
  char* ws = (char*)d_ws;
  u16* wq = (u16*)(ws);                      // 1,572,864
  u16* wp = (u16*)(ws + 1572864);            //   524,288
  u16* ht = (u16*)(ws + 2097152);            // 16,777,216 (reused as aoT)
  u16* qkvo = (u16*)(ws + 18874368);         // 50,331,648 (only v band used)
  u16* qT = (u16*)(ws + 69206016);           // 16,777,216
  u16* kT = (u16*)(ws + 85983232);           // 16,777,216
  u16* aoT = ht;

  prep_kernel<<<4608, 256, 0, stream>>>(qkv_w, proj_w, wq, wp, x, gamma, beta, ht);
  gemm_kernel<0><<<dim3(128, 12), 256, 0, stream>>>(wq, ht, qkv_b, qkvo, qT, kT, nullptr, nullptr);
  attn_kernel<<<512, 512, 0, stream>>>(qT, kT, qkvo, aoT);
  gemm_kernel<1><<<dim3(128, 4), 256, 0, stream>>>(wp, aoT, proj_b, nullptr, nullptr, nullptr, x, out);
}

// Round 21
// 117.157 us; speedup vs baseline: 1.0430x; 1.0199x over previous
//
#include <hip/hip_runtime.h>

typedef unsigned short u16;
typedef unsigned int u32;
typedef __bf16 bf16x8 __attribute__((ext_vector_type(8)));
typedef float f32x4 __attribute__((ext_vector_type(4)));
typedef float f32x16 __attribute__((ext_vector_type(16)));

#define B_ 16
#define C_ 512
#define N_ 1024
#define NB_ 16384   // B_*N_
#define K_ 512
#define M3_ 1536
#define SCALE_Q 0.18033688011112042f  // 0.125 * log2(e)

// ---- helpers ----
__device__ __forceinline__ u16 f2bf(float f) {
  u32 u = __float_as_uint(f);
  u32 r = (u + 0x7FFFu + ((u >> 16) & 1u)) >> 16;  // RNE
  return (u16)r;
}

__device__ __forceinline__ void gl_lds16(const void* g, void* l) {
  __builtin_amdgcn_global_load_lds(
      (const __attribute__((address_space(1))) u32*)(uintptr_t)g,
      (__attribute__((address_space(3))) u32*)(u32)(uintptr_t)l, 16, 0, 0);
}

__device__ __forceinline__ u32 cvtpk(float lo, float hi) {
  u32 r;
  asm("v_cvt_pk_bf16_f32 %0, %1, %2" : "=v"(r) : "v"(lo), "v"(hi));
  return r;
}

__device__ __forceinline__ float exp2a(float x) {
  float r;
  asm("v_exp_f32 %0, %1" : "=v"(r) : "v"(x));
  return r;
}

// (a,b) -> a' = {a_lo, b_lo}, b' = {a_hi, b_hi}
__device__ __forceinline__ void plswap2(u32& a, u32& b) {
#if __has_builtin(__builtin_amdgcn_permlane32_swap)
  auto r = __builtin_amdgcn_permlane32_swap((int)a, (int)b, false, false);
  a = (u32)r[0];
  b = (u32)r[1];
#else
  asm("v_permlane32_swap_b32 %0, %1" : "+v"(a), "+v"(b));
#endif
}

__device__ __forceinline__ float xhalf_sum(float x) {
  u32 a = __float_as_uint(x), b = a;
  plswap2(a, b);
  return __uint_as_float(a) + __uint_as_float(b);
}

// ---- kernel 1: fused weight-cast (blocks 0..4095) + GroupNorm (4096..4607) ----
__global__ __launch_bounds__(256) void prep_kernel(const float* __restrict__ qkv_w,
                                                   const float* __restrict__ proj_w,
                                                   u16* __restrict__ wq,
                                                   u16* __restrict__ wp,
                                                   const float* __restrict__ x,
                                                   const float* __restrict__ gamma,
                                                   const float* __restrict__ beta,
                                                   u16* __restrict__ ht) {
  int blk0 = blockIdx.x;
  int t = threadIdx.x;
  if (blk0 < 4096) {
    int i = blk0 * 256 + t;
    if (i < M3_ * K_) {
      wq[i] = f2bf(qkv_w[i]);
    } else {
      int j = i - M3_ * K_;
      if (j < C_ * K_) wp[j] = f2bf(proj_w[j]);
    }
    return;
  }
  int blk = blk0 - 4096;
  int b = blk >> 5, g = blk & 31;
  const float* xb = x + ((size_t)(b * C_ + g * 16) << 10);
  float v[16][4];
  float s = 0.f, sq = 0.f;
#pragma unroll
  for (int cc = 0; cc < 16; ++cc) {
#pragma unroll
    for (int r = 0; r < 4; ++r) {
      float f = xb[cc * 1024 + r * 256 + t];
      v[cc][r] = f; s += f; sq += f * f;
    }
  }
#pragma unroll
  for (int m = 32; m >= 1; m >>= 1) { s += __shfl_xor(s, m, 64); sq += __shfl_xor(sq, m, 64); }
  __shared__ float red[8];
  int w = t >> 6;
  if ((t & 63) == 0) { red[w * 2] = s; red[w * 2 + 1] = sq; }
  __syncthreads();
  s = red[0] + red[2] + red[4] + red[6];
  sq = red[1] + red[3] + red[5] + red[7];
  float mean = s * (1.f / 16384.f);
  float var = sq * (1.f / 16384.f) - mean * mean;
  float rstd = rsqrtf(var + 1e-5f);
  float gm[16], bt[16];
#pragma unroll
  for (int cc = 0; cc < 16; ++cc) {
    gm[cc] = gamma[g * 16 + cc] * rstd;
    bt[cc] = beta[g * 16 + cc];
  }
  u16* hb = ht + ((size_t)(b << 10)) * C_ + g * 16;
#pragma unroll
  for (int r = 0; r < 4; ++r) {
    u32 pk[8];
#pragma unroll
    for (int q = 0; q < 8; ++q) {
      float f0 = (v[2 * q][r] - mean) * gm[2 * q] + bt[2 * q];
      float f1 = (v[2 * q + 1][r] - mean) * gm[2 * q + 1] + bt[2 * q + 1];
      pk[q] = (u32)f2bf(f0) | ((u32)f2bf(f1) << 16);
    }
    u16* dp = hb + (size_t)(r * 256 + t) * C_;
    uint4 a = {pk[0], pk[1], pk[2], pk[3]};
    uint4 b4 = {pk[4], pk[5], pk[6], pk[7]};
    *(uint4*)dp = a;
    *(uint4*)(dp + 8) = b4;
  }
}

// ---- GEMM: 16-phase counted-vmcnt pipeline, 128x128 tile, 8 WAVES ----
// Same LDS/swizzle/race discipline as r18; waves re-partitioned 4->8 (512
// threads): wave tile 32x64 (acc 2x4), staging 2 instrs/wave/phase, steady
// vmcnt(4) (2 phases x 2 loads in flight), tail 4->2->0. 64KB LDS -> 2
// blocks/CU -> 16 waves/CU = 4/SIMD (2x TLP of the 4-wave version).
// EPI 0: qkv GEMM. q,k bands (rows<1024) stored TRANSPOSED per-(b,h) as (n,d)
//        bf16 into qTo/kTo (q pre-scaled); v band stored (o, bn) in Co.
// EPI 1: out = x + val + bias -> fp32 (b,c,n)
template <int EPI>
__global__ __launch_bounds__(512) void gemm_kernel(const u16* __restrict__ A,
                                                   const u16* __restrict__ BT,
                                                   const float* __restrict__ bias,
                                                   u16* __restrict__ Co,
                                                   u16* __restrict__ qTo,
                                                   u16* __restrict__ kTo,
                                                   const float* __restrict__ xres,
                                                   float* __restrict__ Fo) {
  __shared__ __attribute__((aligned(16))) u16 lds[4][8192];  // [half-buf][A:0..4095 | B:4096..8191]
  int t = threadIdx.x;
  int l = t & 63, w = t >> 6;       // w in 0..7
  int wr = w >> 1, wc = w & 1;      // wr 0..3 (32-row strip), wc 0..1 (64-col strip)
  int lid = blockIdx.y * 128 + blockIdx.x;
  int xcd = lid & 7, j2 = lid >> 3;
  int bx = xcd * 16 + (j2 & 15);
  int by = j2 >> 4;
  int ro0 = by * 128, co0 = bx * 128;
  f32x4 acc[2][4];
#pragma unroll
  for (int m = 0; m < 2; ++m)
#pragma unroll
    for (int n = 0; n < 4; ++n) acc[m][n] = {0.f, 0.f, 0.f, 0.f};

  // staging: 16 x 1KB instrs per phase (8 A + 8 B); wave w issues 2.
  // waves 0-3: A instrs {2w,2w+1} (rows 32w..32w+32); waves 4-7: B likewise.
  // instr covers 16 rows: lane l -> row base+(l>>2), slot l&3, src granule
  // (l&3)^((l>>3)&3)  (key(row)=(row>>1)&3; base mult of 16 -> key=(l>>3)&3).
  int gsrc = ((l & 3) ^ ((l >> 3) & 3)) * 8;
  const u16 *s0, *s1;
  u32 d0s, d1s;
  if (w < 4) {
    s0 = A + (size_t)(ro0 + 32 * w + (l >> 2)) * K_ + gsrc;
    s1 = s0 + (size_t)16 * K_;
    d0s = (2 * w) * 512; d1s = (2 * w + 1) * 512;
  } else {
    int j = w - 4;
    s0 = BT + (size_t)(co0 + 32 * j + (l >> 2)) * K_ + gsrc;
    s1 = s0 + (size_t)16 * K_;
    d0s = 4096 + (2 * j) * 512; d1s = 4096 + (2 * j + 1) * 512;
  }

  auto stage = [&](int hb) {
    u16* base = &lds[hb][0];
    gl_lds16(s0, base + d0s);
    gl_lds16(s1, base + d1s);
    s0 += 32; s1 += 32;
  };

  // read: A row = wr*32 + m*16 + (l&15); B row = wc*64 + n*16 + (l&15);
  // slot = (l>>4)^((l>>1)&3)  (bases are multiples of 16 -> key=(l>>1)&3)
  u32 slot = (((l >> 4) ^ (l >> 1)) & 3) * 8;
  u32 aro = (wr * 32 + (l & 15)) * 32 + slot;
  u32 bro = 4096 + (wc * 64 + (l & 15)) * 32 + slot;

  auto compute = [&](int hb) {
    const u16* base = &lds[hb][0];
    bf16x8 af[2], bfr[4];
#pragma unroll
    for (int m = 0; m < 2; ++m) af[m] = *(const bf16x8*)(base + aro + m * 512);
#pragma unroll
    for (int n = 0; n < 4; ++n) bfr[n] = *(const bf16x8*)(base + bro + n * 512);
    __builtin_amdgcn_s_setprio(1);
#pragma unroll
    for (int m = 0; m < 2; ++m)
#pragma unroll
      for (int n = 0; n < 4; ++n)
        acc[m][n] = __builtin_amdgcn_mfma_f32_16x16x32_bf16(af[m], bfr[n], acc[m][n], 0, 0, 0);
    __builtin_amdgcn_s_setprio(0);
  };

#define PHASE_SYNC(N)                                    \
  asm volatile("s_waitcnt vmcnt(" #N ")" ::: "memory"); \
  __builtin_amdgcn_sched_barrier(0);                     \
  __builtin_amdgcn_s_barrier();                          \
  __builtin_amdgcn_sched_barrier(0);

  stage(0);
  stage(1);
  stage(2);
#pragma unroll 1
  for (int h = 0; h < 13; ++h) {
    PHASE_SYNC(4)
    stage((h + 3) & 3);
    compute(h & 3);
  }
  PHASE_SYNC(4)
  compute(1);  // h=13
  PHASE_SYNC(2)
  compute(2);  // h=14
  PHASE_SYNC(0)
  compute(3);  // h=15
#undef PHASE_SYNC

  if (EPI == 0 && ro0 < 1024) {
    int sel = ro0 >> 9;
    u16* dstb = sel ? kTo : qTo;
    float scl = sel ? 1.f : SCALE_Q;
#pragma unroll
    for (int m = 0; m < 2; ++m) {
      int row0 = ro0 + wr * 32 + m * 16 + (l >> 4) * 4;
      int o = row0 & 511;
      int h2 = o >> 6, d0 = o & 63;
      float bv0 = bias[row0], bv1 = bias[row0 + 1];
      float bv2 = bias[row0 + 2], bv3 = bias[row0 + 3];
#pragma unroll
      for (int n = 0; n < 4; ++n) {
        int col = co0 + wc * 64 + n * 16 + (l & 15);
        int bb = col >> 10, nn = col & 1023;
        float v0 = (acc[m][n][0] + bv0) * scl;
        float v1 = (acc[m][n][1] + bv1) * scl;
        float v2 = (acc[m][n][2] + bv2) * scl;
        float v3 = (acc[m][n][3] + bv3) * scl;
        uint2 ov = {cvtpk(v0, v1), cvtpk(v2, v3)};
        *(uint2*)(dstb + ((size_t)((bb * 8 + h2) << 10) + nn) * 64 + d0) = ov;
      }
    }
  } else {
#pragma unroll
    for (int m = 0; m < 2; ++m) {
#pragma unroll
      for (int j = 0; j < 4; ++j) {
        int row = ro0 + wr * 32 + m * 16 + (l >> 4) * 4 + j;
        float bv = bias[row];
#pragma unroll
        for (int n = 0; n < 4; ++n) {
          int col = co0 + wc * 64 + n * 16 + (l & 15);
          float val = acc[m][n][j] + bv;
          if (EPI == 0) {
            Co[(size_t)row * NB_ + col] = f2bf(val);
          } else {
            int bb = col >> 10, nn = col & 1023;
            size_t oi = (((size_t)(bb * C_ + row)) << 10) + nn;
            Fo[oi] = xres[oi] + val;
          }
        }
      }
    }
  }
}

// ---- kernel 4: flash attention, 8 waves x 32 q-rows (256 q/block), KVBLK=32 ----
// (r20-exact: best measured attn; T15 pipeline, no setprio, 1 load/wave/step)
__global__ __launch_bounds__(512) void attn_kernel(const u16* __restrict__ qT,
                                                   const u16* __restrict__ kT,
                                                   const u16* __restrict__ qkv,
                                                   u16* __restrict__ aoT) {
  __shared__ u16 KV[3][4096];  // [buf][0..2047 = K(32kv x 64d) | 2048..4095 = V(64d x 32kv)]
  int bid = blockIdx.x;
  int wid = (bid & 7) * 64 + (bid >> 3);  // XCD swizzle (512 blocks, 8 XCDs)
  int qt2 = wid & 3, h = (wid >> 2) & 7, b = wid >> 5;
  int bh = b * 8 + h;
  int t = threadIdx.x, l = t & 63, w = t >> 6;  // w in 0..7
  int lq = l & 31, hi = l >> 5;
  int q0 = qt2 * 256 + w * 32;

  const u16* qbase = qT + ((size_t)(bh << 10) + q0 + lq) * 64 + hi * 8;
  bf16x8 qf[4];
#pragma unroll
  for (int kc = 0; kc < 4; ++kc) qf[kc] = *(const bf16x8*)(qbase + kc * 16);

  f32x16 accO[2];
#pragma unroll
  for (int dt = 0; dt < 2; ++dt)
#pragma unroll
    for (int r = 0; r < 16; ++r) accO[dt][r] = 0.f;
  float lsum = 0.f;

  const u16* src0;
  u32 ldso0;
  int adv;
  if (w < 4) {
    int i0 = w;
    src0 = kT + ((size_t)(bh << 10) + i0 * 8 + (l >> 3)) * 64 + (((l & 7) ^ ((l >> 3) & 7)) * 8);
    ldso0 = i0 * 512;
    adv = 2048;  // 32 kv-rows * 64
  } else {
    int j0 = w - 4;
    src0 = qkv + (size_t)(2 * C_ + h * 64 + j0 * 16 + (l >> 2)) * NB_ + (b << 10) +
           (((l & 3) ^ ((l >> 3) & 3)) * 8);
    ldso0 = 2048 + j0 * 512;
    adv = 32;    // 32 kv-cols
  }

  u32 kfo[4], vfo[4];
#pragma unroll
  for (int kc = 0; kc < 4; ++kc)
    kfo[kc] = lq * 64 + (((2 * kc + hi) ^ (lq & 7)) * 8);
#pragma unroll
  for (int dt = 0; dt < 2; ++dt)
#pragma unroll
    for (int kcc = 0; kcc < 2; ++kcc)
      vfo[dt * 2 + kcc] = 2048 + (dt * 32 + lq) * 32 + (((kcc * 2 + hi) ^ ((lq >> 1) & 3)) * 8);

  auto stageTo = [&](u16* buf) {
    gl_lds16(src0, buf + ldso0);
    src0 += adv;
  };

  auto qk = [&](const u16* buf, f32x16& sc) {
    bf16x8 kf[4];
#pragma unroll
    for (int kc = 0; kc < 4; ++kc) kf[kc] = *(const bf16x8*)(buf + kfo[kc]);
#pragma unroll
    for (int r = 0; r < 16; ++r) sc[r] = 0.f;
#pragma unroll
    for (int kc = 0; kc < 4; ++kc)
      sc = __builtin_amdgcn_mfma_f32_32x32x16_bf16(kf[kc], qf[kc], sc, 0, 0, 0);
  };

  auto finish = [&](const u16* buf, f32x16& sc) {
    bf16x8 vf[4];
#pragma unroll
    for (int j = 0; j < 4; ++j) vf[j] = *(const bf16x8*)(buf + vfo[j]);
    float p0 = 0.f, p1 = 0.f, p2 = 0.f, p3 = 0.f;
#pragma unroll
    for (int r = 0; r < 4; ++r) {
      float e0 = exp2a(sc[4 * r + 0]);
      float e1 = exp2a(sc[4 * r + 1]);
      float e2 = exp2a(sc[4 * r + 2]);
      float e3 = exp2a(sc[4 * r + 3]);
      sc[4 * r + 0] = e0; sc[4 * r + 1] = e1;
      sc[4 * r + 2] = e2; sc[4 * r + 3] = e3;
      p0 += e0; p1 += e1; p2 += e2; p3 += e3;
    }
    lsum += (p0 + p1) + (p2 + p3);
    u32 pk[8];
#pragma unroll
    for (int p = 0; p < 8; ++p) pk[p] = cvtpk(sc[2 * p], sc[2 * p + 1]);
    u32 pfu[2][4];
#pragma unroll
    for (int cc = 0; cc < 2; ++cc) {
      u32 w0 = pk[cc * 4 + 0], w2 = pk[cc * 4 + 2];
      u32 w1 = pk[cc * 4 + 1], w3 = pk[cc * 4 + 3];
      plswap2(w0, w2);
      plswap2(w1, w3);
      pfu[cc][0] = w0; pfu[cc][1] = w1; pfu[cc][2] = w2; pfu[cc][3] = w3;
    }
#pragma unroll
    for (int kcc = 0; kcc < 2; ++kcc)
#pragma unroll
      for (int dt = 0; dt < 2; ++dt) {
        union { u32 u[4]; bf16x8 v; } pf;
        pf.u[0] = pfu[kcc][0]; pf.u[1] = pfu[kcc][1];
        pf.u[2] = pfu[kcc][2]; pf.u[3] = pfu[kcc][3];
        accO[dt] = __builtin_amdgcn_mfma_f32_32x32x16_bf16(vf[dt * 2 + kcc], pf.v, accO[dt], 0, 0, 0);
      }
  };

#define WAITBAR(N)                                       \
  asm volatile("s_waitcnt vmcnt(" #N ")" ::: "memory"); \
  __builtin_amdgcn_sched_barrier(0);                     \
  __builtin_amdgcn_s_barrier();                          \
  __builtin_amdgcn_sched_barrier(0);

  u16* pa = &KV[0][0];
  u16* pb = &KV[1][0];
  u16* pc = &KV[2][0];
  f32x16 scA, scB;

  stageTo(pa);  // tile 0
  stageTo(pb);  // tile 1
  WAITBAR(0)
  qk(pa, scA);  // QK(0)

#pragma unroll 1
  for (int s = 0; s < 15; ++s) {
    WAITBAR(0)
    stageTo(pc);
    qk(pb, scB);
    finish(pa, scA);
    u16* tp = pa; pa = pb; pb = pc; pc = tp;
    WAITBAR(0)
    stageTo(pc);
    qk(pb, scA);
    finish(pa, scB);
    tp = pa; pa = pb; pb = pc; pc = tp;
  }
  WAITBAR(0)
  qk(pb, scB);
  finish(pa, scA);
  pa = pb;
  finish(pa, scB);
#undef WAITBAR

  float inv = 1.0f / xhalf_sum(lsum);
  u16* ob = aoT + ((size_t)((b << 10) + q0 + lq)) * C_ + h * 64;
#pragma unroll
  for (int dt = 0; dt < 2; ++dt)
#pragma unroll
    for (int rg = 0; rg < 4; ++rg) {
      int d0 = dt * 32 + rg * 8 + hi * 4;
      u32 w0 = cvtpk(accO[dt][rg * 4 + 0] * inv, accO[dt][rg * 4 + 1] * inv);
      u32 w1 = cvtpk(accO[dt][rg * 4 + 2] * inv, accO[dt][rg * 4 + 3] * inv);
      uint2 o = {w0, w1};
      *(uint2*)(ob + d0) = o;
    }
}

// ---- launcher ----
extern "C" void kernel_launch(void* const* d_in, const int* in_sizes, int n_in,
                              void* d_out, int out_size, void* d_ws, size_t ws_size,
                              hipStream_t stream) {
  const float* x = (const float*)d_in[0];
  const float* gamma = (const float*)d_in[1];
  const float* beta = (const float*)d_in[2];
  const float* qkv_w = (const float*)d_in[3];
  const float* qkv_b = (const float*)d_in[4];
  const float* proj_w = (const float*)d_in[5];
  const float* proj_b = (const float*)d_in[6];
  float* out = (float*)d_out;
  char* ws = (char*)d_ws;
  u16* wq = (u16*)(ws);                      // 1,572,864
  u16* wp = (u16*)(ws + 1572864);            //   524,288
  u16* ht = (u16*)(ws + 2097152);            // 16,777,216 (reused as aoT)
  u16* qkvo = (u16*)(ws + 18874368);         // 50,331,648 (only v band used)
  u16* qT = (u16*)(ws + 69206016);           // 16,777,216
  u16* kT = (u16*)(ws + 85983232);           // 16,777,216
  u16* aoT = ht;

  prep_kernel<<<4608, 256, 0, stream>>>(qkv_w, proj_w, wq, wp, x, gamma, beta, ht);
  gemm_kernel<0><<<dim3(128, 12), 512, 0, stream>>>(wq, ht, qkv_b, qkvo, qT, kT, nullptr, nullptr);
  attn_kernel<<<512, 512, 0, stream>>>(qT, kT, qkvo, aoT);
  gemm_kernel<1><<<dim3(128, 4), 512, 0, stream>>>(wp, aoT, proj_b, nullptr, nullptr, nullptr, x, out);
}